// Round 2
// baseline (321.403 us; speedup 1.0000x reference)
//
#include <hip/hip_runtime.h>
#include <hip/hip_bf16.h>

typedef float  float4v __attribute__((ext_vector_type(4)));
typedef short  short8v __attribute__((ext_vector_type(8)));
typedef short  short4v __attribute__((ext_vector_type(4)));
typedef __bf16 bf16x8  __attribute__((ext_vector_type(8)));
typedef float  f32x4   __attribute__((ext_vector_type(4)));

constexpr int NB = 512, T = 64, DIN = 1024, DOUT = 1024;

// ---- workspace layout (bf16-DMA path) ----
constexpr size_t ABF_BYTES = (size_t)NB * T * DIN * 2;   // 67,108,864
constexpr size_t WN_BYTES  = (size_t)DOUT * DIN * 2;     // 2,097,152
constexpr size_t WS_BF16   = ABF_BYTES + WN_BYTES;       // ~69 MB

__device__ __forceinline__ short f2bf_rne(float x) {
    return __builtin_bit_cast(short, __float2bfloat16(x));
}
__device__ __forceinline__ short f2bf_trunc(float x) {   // exact for {0,1}
    return (short)(__builtin_bit_cast(unsigned int, x) >> 16);
}
__device__ __forceinline__ void load_lds_16B(const void* g, void* l) {
    __builtin_amdgcn_global_load_lds(
        (const __attribute__((address_space(1))) unsigned int*)g,
        (__attribute__((address_space(3))) unsigned int*)l, 16, 0, 0);
}

// ---- fused prepass: A fp32{0,1} -> bf16 (trunc, exact) AND Wn = bf16(W*ratio)
constexpr int PREP_A_BLOCKS = NB * T * DIN / 8 / 256;    // 16384
constexpr int PREP_W_BLOCKS = DOUT * DIN / 4 / 256;      // 1024

__global__ void __launch_bounds__(256)
prep_fused(const float* __restrict__ A, short* __restrict__ Abf,
           const float* __restrict__ W, const float* __restrict__ gamma,
           const float* __restrict__ rvar, short* __restrict__ Wn) {
    const int b = blockIdx.x;
    if (b < PREP_A_BLOCKS) {
        int idx = b * 256 + threadIdx.x;                 // 8-elem group
        const float4v* p = (const float4v*)A + (size_t)idx * 2;
        float4v v0 = __builtin_nontemporal_load(p);
        float4v v1 = __builtin_nontemporal_load(p + 1);
        short8v s;
        #pragma unroll
        for (int j = 0; j < 4; j++) {
            s[j]     = f2bf_trunc(v0[j]);
            s[j + 4] = f2bf_trunc(v1[j]);
        }
        *((short8v*)Abf + idx) = s;                      // cached: re-read soon
    } else {
        int idx = (b - PREP_A_BLOCKS) * 256 + threadIdx.x;  // float4 group
        int o = idx >> 8;
        float r = gamma[o] / sqrtf(rvar[o]);
        float4v w = ((const float4v*)W)[idx];
        short4v s;
        #pragma unroll
        for (int j = 0; j < 4; j++) s[j] = f2bf_rne(w[j] * r);
        ((short4v*)Wn)[idx] = s;
    }
}

// standalone fold (used by the ws-small fallback path only)
__global__ void __launch_bounds__(256)
fold_w_kernel(const float* __restrict__ W, const float* __restrict__ gamma,
              const float* __restrict__ rvar, short* __restrict__ Wn) {
    int idx = blockIdx.x * 256 + threadIdx.x;
    int o = idx >> 8;
    float r = gamma[o] / sqrtf(rvar[o]);
    float4v w = ((const float4v*)W)[idx];
    short4v s;
    #pragma unroll
    for (int j = 0; j < 4; j++) s[j] = f2bf_rne(w[j] * r);
    ((short4v*)Wn)[idx] = s;
}

// =====================================================================
// main: 256x256 tile, BK=64, 4-phase fine interleave per K-tile,
// 9-slot half-tile ring (16KB units), counted vmcnt(2) at boundaries.
//
// Units: tile t owns u=4t+{0:A0,1:A1,2:B0,3:B1}; slot(u)=u%9 (16KB each).
// Issue (FIFO): prologue u0..u4; tile t: p0 issues {4t+5 (A1,t+1),
//   4t+6 (B0,t+1)}, p1 issues {4t+7 (B1,t+1), 4t+8 (A0,t+2)}.
// Boundary before tile t+1: newest issued = 4t+8 (1 unit = 2 loads) =>
//   s_waitcnt vmcnt(2) + s_barrier guarantees units 4t+4..4t+7 landed
//   for EVERY wave (each wave waits its own loads, then barrier).
// WAR: unit u overwrites slot of u-9 = a tile t-1 unit, whose readers all
//   passed the boundary barrier at end of tile t-1. Ring span at any time
//   = units 4t..4t+8 = 9 distinct slots. No sub-step hazards.
// Staging lead: 2.5-5 phases (~400-800cy) -- covers L2/L3 latency.
// =====================================================================
constexpr int BM2 = 256, BN2 = 256, BK2 = 64;
constexpr int NT2   = DIN / BK2;                  // 16
constexpr int SLOT  = 16384;                      // half-tile bytes (128x64 bf16)
constexpr int NSLOT = 9;
constexpr int RINGB = NSLOT * SLOT;               // 147456

__global__ void __launch_bounds__(512, 2)
snn_gemm_if_256(const short* __restrict__ Abf,  // (N*T, DIN) bf16 {0,1}
                const short* __restrict__ Wn,   // (DOUT, DIN) bf16, BN-folded
                const float* __restrict__ bias, const float* __restrict__ gamma,
                const float* __restrict__ beta, const float* __restrict__ rmean,
                const float* __restrict__ rvar, float* __restrict__ out) {
    __shared__ __align__(16) char sm[RINGB];      // ring; potS aliases after
    __shared__ float bstepS[BN2];

    const int tid = threadIdx.x;
    // XCD-chunked work swizzle: 512 blocks, 64 contiguous work items per XCD
    const int work = (blockIdx.x & 7) * 64 + (blockIdx.x >> 3);
    const int oB = (work & 3) * BN2;              // 4 col-blocks share A panel
    const int rg = work >> 2;                     // A rows rg*256.., samples rg*4..

    if (tid < BN2) {
        int o = oB + tid;
        float r = gamma[o] / sqrtf(rvar[o]);
        bstepS[tid] = ((bias[o] - rmean[o]) * r + beta[o]) * (1.0f / 64.0f);
    }
    // retire bstep global loads so they don't pollute vmcnt accounting
    asm volatile("s_waitcnt vmcnt(0)" ::: "memory");
    __builtin_amdgcn_sched_barrier(0);

    const int lane = tid & 63;
    const int wv   = tid >> 6;
    const int wr   = wv >> 2;                     // M-half (0..1) -> A unit
    const int wc   = wv & 3;                      // N-quarter: unit=wc>>1, half=wc&1
    const int l15  = lane & 15;
    const int quad = lane >> 4;

    // per-thread ds_read base offsets (chunk swizzle: c ^= row&7, row&7==l15&7)
    const int D0 = l15 * 128 + ((quad ^ (l15 & 7)) * 16);          // ks=0
    const int D1 = l15 * 128 + (((4 + quad) ^ (l15 & 7)) * 16);    // ks=1
    const int bWoff = (wc & 1) * 8192;            // row offset inside B unit

    // staging: thread covers slot positions tid and tid+512 of each unit.
    // position s: row=s>>3, lin chunk s&7 holds global chunk (s&7)^(row&7).
    const int row0 = tid >> 3,         ck0 = (tid & 7) ^ (row0 & 7);
    const int row1 = (512 + tid) >> 3, ck1 = ((512 + tid) & 7) ^ (row1 & 7);
    const short* gA0a = Abf + (size_t)(rg * BM2 + row0) * DIN + ck0 * 8;
    const short* gA0b = Abf + (size_t)(rg * BM2 + row1) * DIN + ck1 * 8;
    const short* gA1a = gA0a + (size_t)128 * DIN;
    const short* gA1b = gA0b + (size_t)128 * DIN;
    const short* gB0a = Wn + (size_t)(oB + row0) * DIN + ck0 * 8;
    const short* gB0b = Wn + (size_t)(oB + row1) * DIN + ck1 * 8;
    const short* gB1a = gB0a + (size_t)128 * DIN;
    const short* gB1b = gB0b + (size_t)128 * DIN;

    auto STAGE = [&](const short*& g0, const short*& g1, int dstB) {
        load_lds_16B(g0, sm + dstB + tid * 16);
        load_lds_16B(g1, sm + dstB + 8192 + tid * 16);
        g0 += BK2; g1 += BK2;                     // advance one K-tile (128 B)
    };
    auto LD8 = [&](const char* p) {
        return __builtin_bit_cast(bf16x8, *(const short8v*)p);
    };

    f32x4 acc[8][4] = {};

    // ring bases (uniform): read slots for tile t, write slots for this tile
    int rbA0 = 0, rbA1 = SLOT, rbB0 = 2 * SLOT, rbB1 = 3 * SLOT;
    int wb0 = 5 * SLOT, wb1 = 6 * SLOT, wb2 = 7 * SLOT, wb3 = 8 * SLOT;
    auto adv = [](int& x) { x += 4 * SLOT; if (x >= RINGB) x -= RINGB; };

    // prologue: units 0..4 in FIFO order, then land units 0..3
    STAGE(gA0a, gA0b, 0);
    STAGE(gA1a, gA1b, SLOT);
    STAGE(gB0a, gB0b, 2 * SLOT);
    STAGE(gB1a, gB1b, 3 * SLOT);
    STAGE(gA0a, gA0b, 4 * SLOT);
    asm volatile("s_waitcnt vmcnt(2)" ::: "memory");
    __builtin_amdgcn_sched_barrier(0);
    __builtin_amdgcn_s_barrier();
    __builtin_amdgcn_sched_barrier(0);

    #pragma unroll 1
    for (int t = 0; t < NT2; ++t) {
        const char* pA = sm + (wr ? rbA1 : rbA0);
        const char* pB = sm + ((wc & 2) ? rbB1 : rbB0) + bWoff;
        bf16x8 af[4][2], bfv[2][2], bf2[2][2];

        // ---- phase 0: quadrant (mh=0, nh=0) ----
        if (t < NT2 - 1) { STAGE(gA1a, gA1b, wb0); STAGE(gB0a, gB0b, wb1); }
        #pragma unroll
        for (int mi = 0; mi < 4; mi++) {
            af[mi][0] = LD8(pA + mi * 2048 + D0);
            af[mi][1] = LD8(pA + mi * 2048 + D1);
        }
        #pragma unroll
        for (int ni = 0; ni < 2; ni++) {
            bfv[ni][0] = LD8(pB + ni * 2048 + D0);
            bfv[ni][1] = LD8(pB + ni * 2048 + D1);
        }
        __builtin_amdgcn_s_barrier();
        __builtin_amdgcn_s_setprio(1);
        #pragma unroll
        for (int mi = 0; mi < 4; mi++)
            #pragma unroll
            for (int ni = 0; ni < 2; ni++)
                #pragma unroll
                for (int ks = 0; ks < 2; ks++)
                    acc[mi][ni] = __builtin_amdgcn_mfma_f32_16x16x32_bf16(
                        af[mi][ks], bfv[ni][ks], acc[mi][ni], 0, 0, 0);
        __builtin_amdgcn_s_setprio(0);
        __builtin_amdgcn_s_barrier();

        // ---- phase 1: quadrant (mh=0, nh=1) ----
        if (t < NT2 - 1) STAGE(gB1a, gB1b, wb2);
        if (t < NT2 - 2) STAGE(gA0a, gA0b, wb3);
        #pragma unroll
        for (int ni = 0; ni < 2; ni++) {
            bf2[ni][0] = LD8(pB + (2 + ni) * 2048 + D0);
            bf2[ni][1] = LD8(pB + (2 + ni) * 2048 + D1);
        }
        __builtin_amdgcn_s_barrier();
        __builtin_amdgcn_s_setprio(1);
        #pragma unroll
        for (int mi = 0; mi < 4; mi++)
            #pragma unroll
            for (int ni = 0; ni < 2; ni++)
                #pragma unroll
                for (int ks = 0; ks < 2; ks++)
                    acc[mi][2 + ni] = __builtin_amdgcn_mfma_f32_16x16x32_bf16(
                        af[mi][ks], bf2[ni][ks], acc[mi][2 + ni], 0, 0, 0);
        __builtin_amdgcn_s_setprio(0);
        __builtin_amdgcn_s_barrier();

        // ---- phase 2: quadrant (mh=1, nh=0) ----
        #pragma unroll
        for (int mi = 0; mi < 4; mi++) {
            af[mi][0] = LD8(pA + (4 + mi) * 2048 + D0);
            af[mi][1] = LD8(pA + (4 + mi) * 2048 + D1);
        }
        __builtin_amdgcn_s_barrier();
        __builtin_amdgcn_s_setprio(1);
        #pragma unroll
        for (int mi = 0; mi < 4; mi++)
            #pragma unroll
            for (int ni = 0; ni < 2; ni++)
                #pragma unroll
                for (int ks = 0; ks < 2; ks++)
                    acc[4 + mi][ni] = __builtin_amdgcn_mfma_f32_16x16x32_bf16(
                        af[mi][ks], bfv[ni][ks], acc[4 + mi][ni], 0, 0, 0);
        __builtin_amdgcn_s_setprio(0);
        __builtin_amdgcn_s_barrier();

        // ---- phase 3: quadrant (mh=1, nh=1) ----
        __builtin_amdgcn_s_setprio(1);
        #pragma unroll
        for (int mi = 0; mi < 4; mi++)
            #pragma unroll
            for (int ni = 0; ni < 2; ni++)
                #pragma unroll
                for (int ks = 0; ks < 2; ks++)
                    acc[4 + mi][2 + ni] = __builtin_amdgcn_mfma_f32_16x16x32_bf16(
                        af[mi][ks], bf2[ni][ks], acc[4 + mi][2 + ni], 0, 0, 0);
        __builtin_amdgcn_s_setprio(0);

        // ---- tile boundary: counted vmcnt (never 0 except before last tile)
        if (t == NT2 - 2) {
            asm volatile("s_waitcnt vmcnt(0)" ::: "memory");
        } else {
            asm volatile("s_waitcnt vmcnt(2)" ::: "memory");
        }
        __builtin_amdgcn_sched_barrier(0);
        __builtin_amdgcn_s_barrier();
        __builtin_amdgcn_sched_barrier(0);

        adv(rbA0); adv(rbA1); adv(rbB0); adv(rbB1);
        adv(wb0);  adv(wb1);  adv(wb2);  adv(wb3);
    }

    __syncthreads();                              // full drain; potS aliases ring

    // epilogue: 2 rounds of 2 samples (128 rows x 256 cols fp32 = 128 KB LDS)
    float* potS = (float*)sm;
    #pragma unroll 1
    for (int rd = 0; rd < 2; ++rd) {
        if (wr == rd) {                           // this wave's 128 rows
            #pragma unroll
            for (int mi = 0; mi < 8; mi++)
                #pragma unroll
                for (int ni = 0; ni < 4; ni++)
                    #pragma unroll
                    for (int r = 0; r < 4; r++) {
                        int rowl = mi * 16 + quad * 4 + r;
                        int col  = (wc * 64 + ni * 16 + l15) ^ (quad << 3);
                        potS[rowl * BN2 + col] = acc[mi][ni][r];
                    }
        }
        __syncthreads();
        {
            int sl = tid >> 8;                    // 0..1: sample within round
            int c  = tid & 255;
            int n  = rg * 4 + rd * 2 + sl;
            float pot = 0.f, cnt = 0.f;
            const float bst = bstepS[c];
            float* so = out + (size_t)n * T * DOUT + oB + c;
            for (int tt = 0; tt < T; tt++) {
                pot += potS[(sl * 64 + tt) * BN2 + (c ^ (((tt >> 2) & 3) << 3))] + bst;
                float spk = (pot >= 1.0f) ? 1.0f : 0.0f;
                pot -= spk;
                cnt += spk;
                __builtin_nontemporal_store(spk, so + (size_t)tt * DOUT);
            }
            __builtin_nontemporal_store(
                cnt, out + (size_t)NB * T * DOUT + (size_t)n * DOUT + oB + c);
        }
        __syncthreads();
    }
}

// ===================== fallback (round-2 proven path) =====================

constexpr int BM = 128, BN = 128, BK = 64;
constexpr int LDA_F = 72;
constexpr int A_BYTES_F = BM * LDA_F * 2;
constexpr int SMEM_F = A_BYTES_F + BN * BK * 2;

template <bool PREFOLD>
__global__ void __launch_bounds__(256)
snn_gemm_if(const float* __restrict__ A, const float* __restrict__ W,
            const short* __restrict__ Wn,
            const float* __restrict__ bias, const float* __restrict__ gamma,
            const float* __restrict__ beta, const float* __restrict__ rmean,
            const float* __restrict__ rvar, float* __restrict__ out) {
    __shared__ __align__(16) char smem[SMEM_F];
    __shared__ float ratioS[BN];
    __shared__ float bstepS[BN];
    short* AsS  = (short*)smem;
    short* BsS  = (short*)(smem + A_BYTES_F);
    float* potS = (float*)smem;

    const int tid   = threadIdx.x;
    const int by    = blockIdx.y;
    const int oBase = blockIdx.x * BN;

    if (tid < BN) {
        int o = oBase + tid;
        float r = gamma[o] / sqrtf(rvar[o]);
        ratioS[tid] = r;
        bstepS[tid] = ((bias[o] - rmean[o]) * r + beta[o]) * (1.0f / 64.0f);
    }
    __syncthreads();

    const int lane = tid & 63;
    const int wv   = tid >> 6;
    const int wr   = wv & 1;
    const int wc   = wv >> 1;
    const int l15  = lane & 15;
    const int quad = lane >> 4;

    f32x4 acc[4][4] = {};
    const float* Ab = A + (size_t)by * BM * DIN;

    for (int kb = 0; kb < DIN; kb += BK) {
        float4v av[4][2];
        #pragma unroll
        for (int i = 0; i < 4; i++) {
            int g = i * 256 + tid;
            int r = g >> 3, k8 = g & 7;
            const float4v* p = (const float4v*)(Ab + (size_t)r * DIN + kb + k8 * 8);
            av[i][0] = p[0];
            av[i][1] = p[1];
        }
        float4v bv[4][2];
        if constexpr (!PREFOLD) {
            #pragma unroll
            for (int i = 0; i < 4; i++) {
                int slot = i * 256 + tid;
                int r = slot >> 3, k8 = (slot & 7) ^ (r & 7);
                const float4v* p = (const float4v*)(W + (size_t)(oBase + r) * DIN + kb + k8 * 8);
                bv[i][0] = p[0];
                bv[i][1] = p[1];
            }
        }
        __syncthreads();

        if constexpr (PREFOLD) {
            #pragma unroll
            for (int i = 0; i < 4; i++) {
                int slot = i * 256 + tid;
                int r = slot >> 3, k8 = (slot & 7) ^ (r & 7);
                load_lds_16B(Wn + (size_t)(oBase + r) * DIN + kb + k8 * 8,
                             BsS + (size_t)slot * 8);
            }
        } else {
            #pragma unroll
            for (int i = 0; i < 4; i++) {
                int slot = i * 256 + tid;
                int r = slot >> 3;
                float rt = ratioS[r];
                short8v s;
                #pragma unroll
                for (int j = 0; j < 4; j++) {
                    s[j]     = f2bf_rne(bv[i][0][j] * rt);
                    s[j + 4] = f2bf_rne(bv[i][1][j] * rt);
                }
                *(short8v*)(BsS + (size_t)slot * 8) = s;
            }
        }
        #pragma unroll
        for (int i = 0; i < 4; i++) {
            int g = i * 256 + tid;
            int r = g >> 3, k8 = g & 7;
            short8v s;
            #pragma unroll
            for (int j = 0; j < 4; j++) {
                s[j]     = f2bf_trunc(av[i][0][j]);
                s[j + 4] = f2bf_trunc(av[i][1][j]);
            }
            *(short8v*)(&AsS[r * LDA_F + k8 * 8]) = s;
        }
        __syncthreads();

        #pragma unroll
        for (int ks = 0; ks < 2; ks++) {
            bf16x8 af[4], bfv[4];
            #pragma unroll
            for (int mi = 0; mi < 4; mi++)
                af[mi] = __builtin_bit_cast(bf16x8,
                    *(const short8v*)(&AsS[(wr * 64 + mi * 16 + l15) * LDA_F + ks * 32 + quad * 8]));
            #pragma unroll
            for (int ni = 0; ni < 4; ni++) {
                int row  = wc * 64 + ni * 16 + l15;
                int slot = row * 8 + ((ks * 4 + quad) ^ (l15 & 7));
                bfv[ni] = __builtin_bit_cast(bf16x8, *(const short8v*)(BsS + (size_t)slot * 8));
            }
            #pragma unroll
            for (int mi = 0; mi < 4; mi++)
                #pragma unroll
                for (int ni = 0; ni < 4; ni++)
                    acc[mi][ni] = __builtin_amdgcn_mfma_f32_16x16x32_bf16(
                        af[mi], bfv[ni], acc[mi][ni], 0, 0, 0);
        }
    }

    __syncthreads();

    #pragma unroll 1
    for (int s = 0; s < 2; s++) {
        if (wr == s) {
            #pragma unroll
            for (int mi = 0; mi < 4; mi++)
                #pragma unroll
                for (int ni = 0; ni < 4; ni++)
                    #pragma unroll
                    for (int r = 0; r < 4; r++)
                        potS[(mi * 16 + quad * 4 + r) * BN + wc * 64 + ni * 16 + l15] =
                            acc[mi][ni][r];
        }
        __syncthreads();
        if (tid < BN) {
            int n = by * 2 + s;
            float pot = 0.f, cnt = 0.f;
            const float bst = bstepS[tid];
            float* so = out + (size_t)n * T * DOUT + oBase + tid;
            for (int t = 0; t < T; t++) {
                pot += potS[t * BN + tid] + bst;
                float spk = (pot >= 1.0f) ? 1.0f : 0.0f;
                pot -= spk;
                cnt += spk;
                so[(size_t)t * DOUT] = spk;
            }
            out[(size_t)NB * T * DOUT + (size_t)n * DOUT + oBase + tid] = cnt;
        }
        __syncthreads();
    }
}

extern "C" void kernel_launch(void* const* d_in, const int* in_sizes, int n_in,
                              void* d_out, int out_size, void* d_ws, size_t ws_size,
                              hipStream_t stream) {
    const float* A     = (const float*)d_in[0];
    // d_in[1] (input_features_sc) feeds only the un-returned ANN path — dead.
    const float* W     = (const float*)d_in[2];
    const float* bias  = (const float*)d_in[3];
    const float* gamma = (const float*)d_in[4];
    const float* beta  = (const float*)d_in[5];
    const float* rmean = (const float*)d_in[6];
    const float* rvar  = (const float*)d_in[7];
    float* out = (float*)d_out;

    if (d_ws != nullptr && ws_size >= WS_BF16) {
        short* Abf = (short*)d_ws;
        short* Wn  = (short*)((char*)d_ws + ABF_BYTES);
        prep_fused<<<PREP_A_BLOCKS + PREP_W_BLOCKS, 256, 0, stream>>>(
            A, Abf, W, gamma, rvar, Wn);
        snn_gemm_if_256<<<dim3(512), 512, 0, stream>>>(Abf, Wn, bias, gamma, beta,
                                                       rmean, rvar, out);
    } else if (d_ws != nullptr && ws_size >= WN_BYTES) {
        short* Wn = (short*)d_ws;
        fold_w_kernel<<<DOUT * DIN / 4 / 256, 256, 0, stream>>>(W, gamma, rvar, Wn);
        dim3 grid(DOUT / BN, NB / 2);
        snn_gemm_if<true><<<grid, 256, 0, stream>>>(A, W, Wn, bias, gamma, beta,
                                                    rmean, rvar, out);
    } else {
        dim3 grid(DOUT / BN, NB / 2);
        snn_gemm_if<false><<<grid, 256, 0, stream>>>(A, W, nullptr, bias, gamma, beta,
                                                     rmean, rvar, out);
    }
}